// Round 1
// baseline (346.771 us; speedup 1.0000x reference)
//
#include <hip/hip_runtime.h>
#include <hip/hip_bf16.h>
#include <math.h>

#define NUMC 10000
#define DIMS 128
#define SZM  50
#define FD   512
#define NB   64
#define NL   200
#define NTOK (NB*NL)
#define TPB  8      // tokens per block (prep / fp kernels)
#define NG   2      // m-groups in scan
#define MG   25     // m's per group

// ws layout (float offsets)
#define OFF_K  ((size_t)0)
#define OFF_W  (OFF_K + (size_t)NTOK*DIMS)          // [NTOK][64], group-major: g*32 + mloc
#define OFF_E  (OFF_W + (size_t)NTOK*64)
#define OFF_A  (OFF_E + (size_t)NTOK*DIMS)
#define OFF_PR (OFF_A + (size_t)NTOK*DIMS)          // [NG][NTOK][DIMS]

__device__ __forceinline__ float sigmoidf_(float x){ return 1.0f/(1.0f+expf(-x)); }

__global__ __launch_bounds__(128) void prep_kernel(
    const int* __restrict__ q, const int* __restrict__ r,
    const float* __restrict__ k_emb, const float* __restrict__ v_emb,
    const float* __restrict__ W1, const float* __restrict__ b1,
    const float* __restrict__ W2, const float* __restrict__ b2,
    const float* __restrict__ Mk,
    const float* __restrict__ We, const float* __restrict__ be,
    const float* __restrict__ Wa, const float* __restrict__ ba,
    float* __restrict__ ws)
{
    __shared__ float embk[TPB][FD];
    __shared__ float embv[TPB][FD];
    __shared__ float sk[TPB][DIMS];
    __shared__ float sv[TPB][DIMS];
    __shared__ float red[TPB][SZM];
    __shared__ float exs[TPB][SZM];

    const int tid = threadIdx.x;
    const int base = blockIdx.x * TPB;

    #pragma unroll
    for (int t=0;t<TPB;t++){
        int tok = base + t;
        int qi = q[tok];
        int xi = qi + NUMC * r[tok];
        ((float4*)embk[t])[tid] = ((const float4*)(k_emb + (size_t)qi*FD))[tid];
        ((float4*)embv[t])[tid] = ((const float4*)(v_emb + (size_t)xi*FD))[tid];
    }
    __syncthreads();

    const int d = tid;
    float kacc[TPB], vacc[TPB];
    {
        float bb1 = b1[d], bb2 = b2[d];
        #pragma unroll
        for (int t=0;t<TPB;t++){ kacc[t]=bb1; vacc[t]=bb2; }
    }
    for (int i=0;i<FD;i+=4){
        float wk0 = W1[(i+0)*DIMS+d], wk1 = W1[(i+1)*DIMS+d], wk2 = W1[(i+2)*DIMS+d], wk3 = W1[(i+3)*DIMS+d];
        float wv0 = W2[(i+0)*DIMS+d], wv1 = W2[(i+1)*DIMS+d], wv2 = W2[(i+2)*DIMS+d], wv3 = W2[(i+3)*DIMS+d];
        #pragma unroll
        for (int t=0;t<TPB;t++){
            float4 ek = *((const float4*)&embk[t][i]);
            float4 ev = *((const float4*)&embv[t][i]);
            kacc[t] = fmaf(ek.x,wk0,fmaf(ek.y,wk1,fmaf(ek.z,wk2,fmaf(ek.w,wk3,kacc[t]))));
            vacc[t] = fmaf(ev.x,wv0,fmaf(ev.y,wv1,fmaf(ev.z,wv2,fmaf(ev.w,wv3,vacc[t]))));
        }
    }
    #pragma unroll
    for (int t=0;t<TPB;t++){
        sk[t][d]=kacc[t]; sv[t][d]=vacc[t];
        ws[OFF_K + (size_t)(base+t)*DIMS + d] = kacc[t];
    }
    __syncthreads();

    // logits = k @ Mk^T   (threads 0..49 = m)
    if (tid < SZM){
        for (int t=0;t<TPB;t++){
            float lg=0.f;
            const float* mk = Mk + (size_t)tid*DIMS;
            for (int i=0;i<DIMS;i+=4){
                float4 kk=*((const float4*)&sk[t][i]);
                lg += kk.x*mk[i] + kk.y*mk[i+1] + kk.z*mk[i+2] + kk.w*mk[i+3];
            }
            red[t][tid]=lg;
        }
    }
    __syncthreads();
    if (tid < SZM){
        for (int t=0;t<TPB;t++){
            float mx=-1e30f;
            for (int m=0;m<SZM;m++) mx=fmaxf(mx,red[t][m]);
            exs[t][tid]=expf(red[t][tid]-mx);
        }
    }
    __syncthreads();
    if (tid < SZM){
        int g = (tid >= MG) ? 1 : 0;
        int loc = tid - g*MG + g*32;
        for (int t=0;t<TPB;t++){
            float s=0.f;
            for (int m=0;m<SZM;m++) s += exs[t][m];
            ws[OFF_W + (size_t)(base+t)*64 + loc] = exs[t][tid]/s;
        }
    }

    // e = sigmoid(v@We+be), a = tanh(v@Wa+ba)
    float eacc[TPB], aacc[TPB];
    {
        float bbe = be[d], bba = ba[d];
        #pragma unroll
        for (int t=0;t<TPB;t++){ eacc[t]=bbe; aacc[t]=bba; }
    }
    for (int i=0;i<DIMS;i+=4){
        float we0=We[(i+0)*DIMS+d], we1=We[(i+1)*DIMS+d], we2=We[(i+2)*DIMS+d], we3=We[(i+3)*DIMS+d];
        float wa0=Wa[(i+0)*DIMS+d], wa1=Wa[(i+1)*DIMS+d], wa2=Wa[(i+2)*DIMS+d], wa3=Wa[(i+3)*DIMS+d];
        #pragma unroll
        for (int t=0;t<TPB;t++){
            float4 s4=*((const float4*)&sv[t][i]);
            eacc[t]=fmaf(s4.x,we0,fmaf(s4.y,we1,fmaf(s4.z,we2,fmaf(s4.w,we3,eacc[t]))));
            aacc[t]=fmaf(s4.x,wa0,fmaf(s4.y,wa1,fmaf(s4.z,wa2,fmaf(s4.w,wa3,aacc[t]))));
        }
    }
    #pragma unroll
    for (int t=0;t<TPB;t++){
        size_t o=(size_t)(base+t)*DIMS+d;
        ws[OFF_E+o]=sigmoidf_(eacc[t]);
        ws[OFF_A+o]=tanhf(aacc[t]);
    }
}

__global__ __launch_bounds__(128) void scan_kernel(const float* __restrict__ Mv0, float* __restrict__ ws)
{
    const int b = blockIdx.x;
    const int g = blockIdx.y;
    const int d = threadIdx.x;

    const float* wb = ws + OFF_W + (size_t)b*NL*64 + g*32;
    const float* eb = ws + OFF_E + (size_t)b*NL*DIMS + d;
    const float* ab = ws + OFF_A + (size_t)b*NL*DIMS + d;
    float* pr = ws + OFF_PR + ((size_t)g*NTOK + (size_t)b*NL)*DIMS + d;

    float Mv[MG];
    #pragma unroll
    for (int m=0;m<MG;m++) Mv[m] = Mv0[(g*MG+m)*DIMS + d];

    float wA[MG], wB[MG];
    float eA,aA,eB,aB;
    #pragma unroll
    for (int m=0;m<MG;m++) wA[m]=wb[m];
    eA=eb[0]; aA=ab[0];

    for (int t=0;t<NL;t+=2){
        // prefetch t+1 (always valid: t even <= 198)
        #pragma unroll
        for (int m=0;m<MG;m++) wB[m]=wb[(size_t)(t+1)*64+m];
        eB=eb[(size_t)(t+1)*DIMS]; aB=ab[(size_t)(t+1)*DIMS];

        float rt=0.f;
        #pragma unroll
        for (int m=0;m<MG;m++){
            float c=wA[m];
            rt=fmaf(c,Mv[m],rt);
            float t1=c*eA, t2=c*aA;
            Mv[m]=Mv[m]+fmaf(-t1,Mv[m],t2);
        }
        pr[(size_t)t*DIMS]=rt;

        if (t+2<NL){
            #pragma unroll
            for (int m=0;m<MG;m++) wA[m]=wb[(size_t)(t+2)*64+m];
            eA=eb[(size_t)(t+2)*DIMS]; aA=ab[(size_t)(t+2)*DIMS];
        }

        rt=0.f;
        #pragma unroll
        for (int m=0;m<MG;m++){
            float c=wB[m];
            rt=fmaf(c,Mv[m],rt);
            float t1=c*eB, t2=c*aB;
            Mv[m]=Mv[m]+fmaf(-t1,Mv[m],t2);
        }
        pr[(size_t)(t+1)*DIMS]=rt;
    }
}

__global__ __launch_bounds__(128) void fp_kernel(
    const float* __restrict__ ws,
    const float* __restrict__ Wf, const float* __restrict__ bf,
    const float* __restrict__ Wp, const float* __restrict__ bp,
    float* __restrict__ out)
{
    __shared__ float sr[TPB][DIMS];
    __shared__ float skk[TPB][DIMS];
    __shared__ float pf[TPB][DIMS];
    const int tid=threadIdx.x;
    const int base=blockIdx.x*TPB;

    #pragma unroll
    for (int t=0;t<TPB;t++){
        size_t tok=(size_t)base+t;
        sr[t][tid]= ws[OFF_PR + tok*DIMS + tid] + ws[OFF_PR + ((size_t)NTOK+tok)*DIMS + tid];
        skk[t][tid]= ws[OFF_K + tok*DIMS + tid];
    }
    __syncthreads();

    const int j=tid;
    float facc[TPB];
    {
        float bfj=bf[j];
        #pragma unroll
        for (int t=0;t<TPB;t++) facc[t]=bfj;
    }
    for (int i=0;i<DIMS;i+=4){
        float wt0=Wf[(i+0)*DIMS+j],wt1=Wf[(i+1)*DIMS+j],wt2=Wf[(i+2)*DIMS+j],wt3=Wf[(i+3)*DIMS+j];
        float wb0=Wf[(DIMS+i+0)*DIMS+j],wb1=Wf[(DIMS+i+1)*DIMS+j],wb2=Wf[(DIMS+i+2)*DIMS+j],wb3=Wf[(DIMS+i+3)*DIMS+j];
        #pragma unroll
        for (int t=0;t<TPB;t++){
            float4 r4=*((const float4*)&sr[t][i]);
            float4 k4=*((const float4*)&skk[t][i]);
            facc[t]=fmaf(r4.x,wt0,fmaf(r4.y,wt1,fmaf(r4.z,wt2,fmaf(r4.w,wt3,facc[t]))));
            facc[t]=fmaf(k4.x,wb0,fmaf(k4.y,wb1,fmaf(k4.z,wb2,fmaf(k4.w,wb3,facc[t]))));
        }
    }
    {
        float wpj=Wp[j];
        #pragma unroll
        for (int t=0;t<TPB;t++){
            pf[t][j]=tanhf(facc[t])*wpj;
        }
    }
    __syncthreads();
    if (tid<TPB){
        float s=bp[0];
        for (int jj=0;jj<DIMS;jj++) s+=pf[tid][jj];
        out[base+tid]=sigmoidf_(s);
    }
}

extern "C" void kernel_launch(void* const* d_in, const int* in_sizes, int n_in,
                              void* d_out, int out_size, void* d_ws, size_t ws_size,
                              hipStream_t stream)
{
    const int*   q     = (const int*)  d_in[0];
    const int*   r     = (const int*)  d_in[1];
    /* d_in[2] = diff (unused) */
    const float* k_emb = (const float*)d_in[3];
    const float* v_emb = (const float*)d_in[4];
    const float* W1    = (const float*)d_in[5];
    const float* b1    = (const float*)d_in[6];
    const float* W2    = (const float*)d_in[7];
    const float* b2    = (const float*)d_in[8];
    const float* Mk    = (const float*)d_in[9];
    const float* Mv0   = (const float*)d_in[10];
    const float* We    = (const float*)d_in[11];
    const float* be    = (const float*)d_in[12];
    const float* Wa    = (const float*)d_in[13];
    const float* ba    = (const float*)d_in[14];
    const float* Wf    = (const float*)d_in[15];
    const float* bf    = (const float*)d_in[16];
    const float* Wp    = (const float*)d_in[17];
    const float* bp    = (const float*)d_in[18];

    float* ws  = (float*)d_ws;
    float* out = (float*)d_out;

    prep_kernel<<<NTOK/TPB, 128, 0, stream>>>(q,r,k_emb,v_emb,W1,b1,W2,b2,Mk,We,be,Wa,ba,ws);
    scan_kernel<<<dim3(NB,NG), 128, 0, stream>>>(Mv0, ws);
    fp_kernel<<<NTOK/TPB, 128, 0, stream>>>(ws, Wf, bf, Wp, bp, out);
}